// Round 17
// baseline (86.941 us; speedup 1.0000x reference)
//
#include <hip/hip_runtime.h>
#include <stdint.h>

typedef __bf16 bf16_t;
typedef bf16_t __attribute__((ext_vector_type(8))) bf16x8;
typedef float __attribute__((ext_vector_type(4))) f32x4;
typedef float __attribute__((ext_vector_type(16))) f32x16;
typedef unsigned u32;

#define BATCH 4
#define SEQ 1024
#define HIDD 1024
#define NH 16
#define DH 64

// ---------- helpers ----------
__device__ __forceinline__ unsigned short f2bf(float f) {
  unsigned u = __float_as_uint(f);
  u += 0x7fffu + ((u >> 16) & 1u);   // RNE
  return (unsigned short)(u >> 16);
}

__device__ __forceinline__ f32x4 mfma16(bf16x8 a, bf16x8 b, f32x4 c) {
  return __builtin_amdgcn_mfma_f32_16x16x32_bf16(a, b, c, 0, 0, 0);
}
__device__ __forceinline__ f32x16 mfma32(bf16x8 a, bf16x8 b, f32x16 c) {
  return __builtin_amdgcn_mfma_f32_32x32x16_bf16(a, b, c, 0, 0, 0);
}

__device__ __forceinline__ u32 cvtpk(float lo, float hi) {
  u32 r;
  asm("v_cvt_pk_bf16_f32 %0, %1, %2" : "=v"(r) : "v"(lo), "v"(hi));
  return r;
}
__device__ __forceinline__ void plswap(u32& a, u32& b) {
  asm("v_permlane32_swap_b32 %0, %1" : "+v"(a), "+v"(b));
}

// ---------- kernel 1: fused prep -> fragment-packed A and B (R16, measured) ----------
__global__ __launch_bounds__(256) void prep(
    const float* __restrict__ hs, unsigned short* __restrict__ Apack,
    const float* __restrict__ Wq, const float* __restrict__ Wk,
    const float* __restrict__ Wv, unsigned short* __restrict__ Bpack) {
  __shared__ alignas(16) char smem[16 * 1032 * 2];  // 33KB; W branch uses 9.2KB
  const int bid = blockIdx.x;
  const int t = threadIdx.x;
  if (bid < 256) {
    unsigned short(*at)[1032] = (unsigned short(*)[1032])smem;
    const int row = t >> 4, c16 = t & 15;
    const float* src = hs + (size_t)(bid * 16 + row) * 1024;
#pragma unroll
    for (int i = 0; i < 16; ++i) {
      const float4 f = ((const float4*)src)[i * 16 + c16];
      ushort4 o = make_ushort4(f2bf(f.x), f2bf(f.y), f2bf(f.z), f2bf(f.w));
      *(ushort4*)&at[row][(i * 16 + c16) * 4] = o;
    }
    __syncthreads();
    unsigned short* dst = Apack + (size_t)bid * 16384;
#pragma unroll
    for (int j = 0; j < 8; ++j) {
      const int u = j * 256 + t;                  // uint4 index: kt*64 + lg*16 + lc
      const int kt = u >> 6, rem = u & 63, lg = rem >> 4, lc = rem & 15;
      *(uint4*)(dst + (size_t)u * 8) = *(const uint4*)&at[lc][kt * 32 + lg * 8];
    }
    return;
  }
  unsigned short(*tile)[72] = (unsigned short(*)[72])smem;
  const int id = bid - 256;            // 0..767
  const int z = id >> 8, rem = id & 255;
  const int k0 = (rem & 15) * 64, n0 = (rem >> 4) * 64;
  const float* W = (z == 0) ? Wq : (z == 1) ? Wk : Wv;
  unsigned short* o = Bpack + (size_t)z * (1024 * 1024);
  const int r = t >> 6, c = t & 63;
#pragma unroll
  for (int i = 0; i < 16; ++i) {
    const int row = i * 4 + r;
    tile[row][c] = f2bf(W[(size_t)(k0 + row) * 1024 + n0 + c]);
  }
  __syncthreads();
  const int q = t >> 6, l = t & 63, lc = l & 15, lg = l >> 4;
#pragma unroll
  for (int it = 0; it < 2; ++it) {
    const int nt = (rem >> 4) * 4 + q;
    const int kt = (rem & 15) * 2 + it;
    unsigned short buf[8];
#pragma unroll
    for (int e = 0; e < 8; ++e)
      buf[e] = tile[it * 32 + lg * 8 + e][q * 16 + lc];
    *(uint4*)(o + (size_t)nt * 16384 + kt * 512 + l * 8) = *(uint4*)buf;
  }
}

// ---------- kernel 2: QKV GEMM, 8x4 wave tile (128m x 64n), 2-wave blocks ----------
// On-chip-BW analysis: 4x4 tile = 31 B/kFLOP fragment traffic (L1-bound, 25% MFMA);
// 8x4 = 23 B/kFLOP (-25%). Block = 2 waves (wc 0/1) -> 128x128 tile, grid stays
// 768 = 3 blocks/CU balanced. acc 128 + frag sets 96 ~= 240 VGPR (<256, no spill
// expected). Same Apack/Bpack chunks, 2-set prefetch, XCD swizzle as R15/R16.
__global__ __launch_bounds__(128, 2) void qkv_gemm(
    const unsigned short* __restrict__ Apack,
    const unsigned short* __restrict__ Bpack,
    const float* __restrict__ bq, const float* __restrict__ bk,
    const float* __restrict__ bv,
    unsigned short* __restrict__ Qb,
    unsigned short* __restrict__ Kpk,
    unsigned short* __restrict__ Vpk) {
  const int id = blockIdx.x;
  const int xcd = id & 7;
  const int j = id >> 3;
  const int mx = (xcd & 3) * 8 + (j & 7);
  const int v = (j >> 3) * 2 + (xcd >> 2);
  const int nx = v & 7;
  const int z = v >> 3;

  const float* bias = (z == 0) ? bq : (z == 1) ? bk : bv;
  const float scale = (z == 0) ? 0.125f * 1.44269504089f : 1.0f;
  const int m0 = mx * 128, n0 = nx * 128;
  const int t = threadIdx.x;
  const int wc = t >> 6, l = t & 63;
  const int lg = l >> 4, lc = l & 15;

  const unsigned short* Ap = Apack + (size_t)(mx * 8) * 16384 + l * 8;
  const unsigned short* Bp = Bpack + (size_t)z * (1024 * 1024) +
                             (size_t)(nx * 8 + wc * 4) * 16384 + l * 8;

  f32x4 acc[8][4] = {};
  bf16x8 a0[8], b0[4], a1[8], b1[4];

#pragma unroll
  for (int m = 0; m < 8; ++m) a0[m] = *(const bf16x8*)(Ap + m * 16384);
#pragma unroll
  for (int n = 0; n < 4; ++n) b0[n] = *(const bf16x8*)(Bp + n * 16384);

  for (int kk = 0; kk < 16; ++kk) {
    const int kt = kk * 2;
    // prefetch kt+1 -> set1 (hides under set0 MFMAs)
#pragma unroll
    for (int m = 0; m < 8; ++m)
      a1[m] = *(const bf16x8*)(Ap + m * 16384 + (kt + 1) * 512);
#pragma unroll
    for (int n = 0; n < 4; ++n)
      b1[n] = *(const bf16x8*)(Bp + n * 16384 + (kt + 1) * 512);
#pragma unroll
    for (int m = 0; m < 8; ++m)
#pragma unroll
      for (int n = 0; n < 4; ++n)
        acc[m][n] = mfma16(a0[m], b0[n], acc[m][n]);
    // prefetch kt+2 -> set0 (hides under set1 MFMAs)
    if (kk < 15) {
#pragma unroll
      for (int m = 0; m < 8; ++m)
        a0[m] = *(const bf16x8*)(Ap + m * 16384 + (kt + 2) * 512);
#pragma unroll
      for (int n = 0; n < 4; ++n)
        b0[n] = *(const bf16x8*)(Bp + n * 16384 + (kt + 2) * 512);
    }
#pragma unroll
    for (int m = 0; m < 8; ++m)
#pragma unroll
      for (int n = 0; n < 4; ++n)
        acc[m][n] = mfma16(a1[m], b1[n], acc[m][n]);
  }

  if (z == 0) {
#pragma unroll
    for (int n = 0; n < 4; ++n) {
      const int col = n0 + wc * 64 + n * 16 + lc;
      const float bs = bias[col];
#pragma unroll
      for (int m = 0; m < 8; ++m)
#pragma unroll
        for (int r = 0; r < 4; ++r) {
          const int row = m0 + m * 16 + lg * 4 + r;
          Qb[(size_t)row * 1024 + col] = f2bf((acc[m][n][r] + bs) * scale);
        }
    }
  } else if (z == 1) {
    // Kpack: idx = ((bh*32+kb)*4+s)*512 + (lo+hi*32)*8 + e
#pragma unroll
    for (int n = 0; n < 4; ++n) {
      const int col = n0 + wc * 64 + n * 16 + lc;
      const float bs = bias[col];
      const int h = col >> 6, s = (col >> 4) & 3, hi = (col >> 3) & 1, e = col & 7;
#pragma unroll
      for (int m = 0; m < 8; ++m)
#pragma unroll
        for (int r = 0; r < 4; ++r) {
          const int row = m0 + m * 16 + lg * 4 + r;
          const int bh = (row >> 10) * 16 + h, tl = row & 1023;
          const int kb = tl >> 5, lo = tl & 31;
          Kpk[(size_t)(((bh * 32 + kb) * 4 + s) * 512) + (lo + hi * 32) * 8 + e] =
              f2bf(acc[m][n][r] + bs);
        }
    }
  } else {
    // Vpack: idx = ((bh*16+kt)*8+g*4+sv)*512 + (lo+hiv*32)*8 + ev
#pragma unroll
    for (int n = 0; n < 4; ++n) {
      const int col = n0 + wc * 64 + n * 16 + lc;
      const float bs = bias[col];
      const int h = col >> 6, g = (col >> 5) & 1, lo = col & 31;
#pragma unroll
      for (int m = 0; m < 8; ++m)
#pragma unroll
        for (int r = 0; r < 4; ++r) {
          const int row = m0 + m * 16 + lg * 4 + r;
          const int bh = (row >> 10) * 16 + h, tl = row & 1023;
          const int kt = tl >> 6, within = tl & 63;
          const int sv = within >> 4, hiv = (within >> 3) & 1, ev = within & 7;
          Vpk[(size_t)(((bh * 16 + kt) * 8 + g * 4 + sv) * 512) +
              (lo + hiv * 32) * 8 + ev] = f2bf(acc[m][n][r] + bs);
        }
    }
  }
}

// ---------- kernel 3: flash attention (R13/R12/R5 listing verbatim; measured ~24us) ----------
__global__ __launch_bounds__(256, 2) void attn_kernel(
    const unsigned short* __restrict__ Qb,     // (B,S,H,D) bf16, pre-scaled log2e/sqrt(D)
    const unsigned short* __restrict__ Kpack,  // [bh][kb][s][lane] 16B
    const unsigned short* __restrict__ Vpack,  // [bh][kt][g][s][lane] 16B
    const int* __restrict__ amask,             // (B,S)
    const float* __restrict__ lhm,             // (H)
    float* __restrict__ out) {                 // (B,S,HID) fp32
  const int id = blockIdx.x;
  const int swzid = (id & 7) * 64 + (id >> 3);  // 8 bh per XCD
  const int qt = swzid & 7;
  const int bh = swzid >> 3;
  const int b = bh >> 4, h = bh & 15;
  const int t = threadIdx.x;
  const int w = t >> 6, l = t & 63;
  const int lo = l & 31, hi = l >> 5;
  const int q0 = qt * 128 + w * 32;

  const unsigned short* Kp = Kpack + (size_t)bh * 65536 + l * 8;
  const unsigned short* Vp = Vpack + (size_t)bh * 65536 + l * 8;

  const unsigned short* qp = Qb + (size_t)(b * SEQ + q0 + lo) * HIDD + h * DH + hi * 8;
  bf16x8 qf[4];
#pragma unroll
  for (int s = 0; s < 4; ++s) qf[s] = *(const bf16x8*)(qp + s * 16);

  bool needmask;
  {
    unsigned long long mm = ~0ull;
#pragma unroll
    for (int tk = 0; tk < 16; ++tk)
      mm &= __ballot(amask[b * SEQ + tk * 64 + l] > 0);
    needmask = (mm != ~0ull);
  }

  float m_run = -INFINITY, l_run = 0.f;
  f32x16 acc0 = {}, acc1 = {};

  bf16x8 kf0[4], kf1[4], vf0[4], vf1[4];

#pragma unroll
  for (int s = 0; s < 4; ++s) {
    kf0[s] = *(const bf16x8*)(Kp + (s)*512);
    kf1[s] = *(const bf16x8*)(Kp + (4 + s) * 512);
  }

  for (int tk = 0; tk < 16; ++tk) {
#pragma unroll
    for (int s = 0; s < 4; ++s) {
      vf0[s] = *(const bf16x8*)(Vp + (size_t)(tk * 8 + s) * 512);
      vf1[s] = *(const bf16x8*)(Vp + (size_t)(tk * 8 + 4 + s) * 512);
    }

    // ---- S^T = K . Q^T ----
    f32x16 sg0 = {}, sg1 = {};
    __builtin_amdgcn_s_setprio(1);
#pragma unroll
    for (int s = 0; s < 4; ++s) {
      sg0 = mfma32(kf0[s], qf[s], sg0);
      sg1 = mfma32(kf1[s], qf[s], sg1);
    }
    __builtin_amdgcn_s_setprio(0);

    if (tk < 15) {
#pragma unroll
      for (int s = 0; s < 4; ++s) {
        kf0[s] = *(const bf16x8*)(Kp + (size_t)(tk * 8 + 8 + s) * 512);
        kf1[s] = *(const bf16x8*)(Kp + (size_t)(tk * 8 + 12 + s) * 512);
      }
    }

    // ---- row max ----
    float t0[8];
#pragma unroll
    for (int i = 0; i < 8; ++i)
      t0[i] = fmaxf(fmaxf(sg0[i], sg0[i + 8]), fmaxf(sg1[i], sg1[i + 8]));
    float t1 = fmaxf(fmaxf(fmaxf(t0[0], t0[1]), fmaxf(t0[2], t0[3])),
                     fmaxf(fmaxf(t0[4], t0[5]), fmaxf(t0[6], t0[7])));
    const float pmax = fmaxf(t1, __shfl_xor(t1, 32));

    // ---- defer-max (T13) ----
    if (!__all(pmax <= m_run + 8.f)) {
      const float mnew = fmaxf(m_run, pmax);
      const float sc = __builtin_amdgcn_exp2f(m_run - mnew);
      m_run = mnew;
      l_run *= sc;
#pragma unroll
      for (int g = 0; g < 16; ++g) {
        const int rowi = (g & 3) + 8 * (g >> 2) + 4 * hi;
        const float scr = __shfl(sc, rowi);
        acc0[g] *= scr;
        acc1[g] *= scr;
      }
    }

    // ---- p = exp2(s - m) ----
#pragma unroll
    for (int g = 0; g < 16; ++g) {
      sg0[g] = __builtin_amdgcn_exp2f(sg0[g] - m_run);
      sg1[g] = __builtin_amdgcn_exp2f(sg1[g] - m_run);
    }

    // ---- mask (slow path only) ----
    if (needmask) {
      const int mv = amask[b * SEQ + tk * 64 + l];
      const unsigned long long m64 = __ballot(mv > 0);
      if (m64 != ~0ull) {
#pragma unroll
        for (int g = 0; g < 16; ++g) {
          const int krow = (g & 3) + 8 * (g >> 2) + 4 * hi;
          if (!((m64 >> krow) & 1)) sg0[g] = 0.f;
          if (!((m64 >> (krow + 32)) & 1)) sg1[g] = 0.f;
        }
      }
    }

    // ---- row sum ----
    float s0[8];
#pragma unroll
    for (int i = 0; i < 8; ++i)
      s0[i] = (sg0[i] + sg0[i + 8]) + (sg1[i] + sg1[i + 8]);
    float rs = ((s0[0] + s0[1]) + (s0[2] + s0[3])) +
               ((s0[4] + s0[5]) + (s0[6] + s0[7]));
    rs += __shfl_xor(rs, 32);
    l_run += rs;

    // ---- P -> bf16 PA fragments (T12) ----
    auto mk = [](float a0, float a1, float a2, float a3,
                 float a4, float a5, float a6, float a7) -> bf16x8 {
      u32 x = cvtpk(a0, a1), y = cvtpk(a2, a3);
      u32 a = cvtpk(a4, a5), b2 = cvtpk(a6, a7);
      plswap(x, a);
      plswap(y, b2);
      union { u32 u[4]; bf16x8 v; } fu;
      fu.u[0] = x; fu.u[1] = y; fu.u[2] = a; fu.u[3] = b2;
      return fu.v;
    };
    const bf16x8 pa0 = mk(sg0[0], sg0[1], sg0[2], sg0[3], sg0[4], sg0[5], sg0[6], sg0[7]);
    const bf16x8 pa1 = mk(sg0[8], sg0[9], sg0[10], sg0[11], sg0[12], sg0[13], sg0[14], sg0[15]);
    const bf16x8 pa2 = mk(sg1[0], sg1[1], sg1[2], sg1[3], sg1[4], sg1[5], sg1[6], sg1[7]);
    const bf16x8 pa3 = mk(sg1[8], sg1[9], sg1[10], sg1[11], sg1[12], sg1[13], sg1[14], sg1[15]);

    // ---- PV: acc += P . V ----
    __builtin_amdgcn_s_setprio(1);
#pragma unroll
    for (int s = 0; s < 4; ++s) {
      const bf16x8 paf = (s == 0) ? pa0 : (s == 1) ? pa1 : (s == 2) ? pa2 : pa3;
      acc0 = mfma32(paf, vf0[s], acc0);
      acc1 = mfma32(paf, vf1[s], acc1);
    }
    __builtin_amdgcn_s_setprio(0);
  }

  // ---- epilogue ----
  const float hm = lhm[h];
  const float inv = hm / l_run;
  float* ob = out + (size_t)(b * SEQ + q0) * HIDD + h * DH + lo;
#pragma unroll
  for (int g = 0; g < 16; ++g) {
    const int rowi = (g & 3) + 8 * (g >> 2) + 4 * hi;
    const float iv = __shfl(inv, rowi);
    ob[(size_t)rowi * HIDD] = acc0[g] * iv;
    ob[(size_t)rowi * HIDD + 32] = acc1[g] * iv;
  }
}

// ---------- launch ----------
extern "C" void kernel_launch(void* const* d_in, const int* in_sizes, int n_in,
                              void* d_out, int out_size, void* d_ws, size_t ws_size,
                              hipStream_t stream) {
  const float* hs = (const float*)d_in[0];
  const int* amask = (const int*)d_in[1];
  const float* lhm = (const float*)d_in[2];
  const float* Wq = (const float*)d_in[3];
  const float* bq = (const float*)d_in[4];
  const float* Wk = (const float*)d_in[5];
  const float* bk = (const float*)d_in[6];
  const float* Wv = (const float*)d_in[7];
  const float* bv = (const float*)d_in[8];
  float* out = (float*)d_out;

  char* ws = (char*)d_ws;
  unsigned short* Apack = (unsigned short*)ws;                  // 8 MB
  unsigned short* Bpack = (unsigned short*)(ws + (8u << 20));   // 6 MB
  unsigned short* Qb = (unsigned short*)(ws + (14u << 20));     // 8 MB
  unsigned short* Kpk = (unsigned short*)(ws + (22u << 20));    // 8 MB
  unsigned short* Vpk = (unsigned short*)(ws + (30u << 20));    // 8 MB

  prep<<<1024, 256, 0, stream>>>(hs, Apack, Wq, Wk, Wv, Bpack);
  qkv_gemm<<<768, 128, 0, stream>>>(Apack, Bpack, bq, bk, bv, Qb, Kpk, Vpk);
  attn_kernel<<<512, 256, 0, stream>>>(Qb, Kpk, Vpk, amask, lhm, out);
}

// Round 18
// 71.039 us; speedup vs baseline: 1.2239x; 1.2239x over previous
//
#include <hip/hip_runtime.h>
#include <stdint.h>

typedef __bf16 bf16_t;
typedef bf16_t __attribute__((ext_vector_type(8))) bf16x8;
typedef float __attribute__((ext_vector_type(4))) f32x4;
typedef float __attribute__((ext_vector_type(16))) f32x16;
typedef unsigned u32;

#define BATCH 4
#define SEQ 1024
#define HIDD 1024
#define NH 16
#define DH 64

// ---------- helpers ----------
__device__ __forceinline__ unsigned short f2bf(float f) {
  unsigned u = __float_as_uint(f);
  u += 0x7fffu + ((u >> 16) & 1u);   // RNE
  return (unsigned short)(u >> 16);
}

__device__ __forceinline__ f32x4 mfma16(bf16x8 a, bf16x8 b, f32x4 c) {
  return __builtin_amdgcn_mfma_f32_16x16x32_bf16(a, b, c, 0, 0, 0);
}
__device__ __forceinline__ f32x16 mfma32(bf16x8 a, bf16x8 b, f32x16 c) {
  return __builtin_amdgcn_mfma_f32_32x32x16_bf16(a, b, c, 0, 0, 0);
}

__device__ __forceinline__ u32 cvtpk(float lo, float hi) {
  u32 r;
  asm("v_cvt_pk_bf16_f32 %0, %1, %2" : "=v"(r) : "v"(lo), "v"(hi));
  return r;
}
__device__ __forceinline__ void plswap(u32& a, u32& b) {
  asm("v_permlane32_swap_b32 %0, %1" : "+v"(a), "+v"(b));
}

// ---------- kernel 1: fused prep -> fragment-packed A and B (R16, measured) ----------
__global__ __launch_bounds__(256) void prep(
    const float* __restrict__ hs, unsigned short* __restrict__ Apack,
    const float* __restrict__ Wq, const float* __restrict__ Wk,
    const float* __restrict__ Wv, unsigned short* __restrict__ Bpack) {
  __shared__ alignas(16) char smem[16 * 1032 * 2];  // 33KB; W branch uses 9.2KB
  const int bid = blockIdx.x;
  const int t = threadIdx.x;
  if (bid < 256) {
    unsigned short(*at)[1032] = (unsigned short(*)[1032])smem;
    const int row = t >> 4, c16 = t & 15;
    const float* src = hs + (size_t)(bid * 16 + row) * 1024;
#pragma unroll
    for (int i = 0; i < 16; ++i) {
      const float4 f = ((const float4*)src)[i * 16 + c16];
      ushort4 o = make_ushort4(f2bf(f.x), f2bf(f.y), f2bf(f.z), f2bf(f.w));
      *(ushort4*)&at[row][(i * 16 + c16) * 4] = o;
    }
    __syncthreads();
    unsigned short* dst = Apack + (size_t)bid * 16384;
#pragma unroll
    for (int j = 0; j < 8; ++j) {
      const int u = j * 256 + t;                  // uint4 index: kt*64 + lg*16 + lc
      const int kt = u >> 6, rem = u & 63, lg = rem >> 4, lc = rem & 15;
      *(uint4*)(dst + (size_t)u * 8) = *(const uint4*)&at[lc][kt * 32 + lg * 8];
    }
    return;
  }
  unsigned short(*tile)[72] = (unsigned short(*)[72])smem;
  const int id = bid - 256;            // 0..767
  const int z = id >> 8, rem = id & 255;
  const int k0 = (rem & 15) * 64, n0 = (rem >> 4) * 64;
  const float* W = (z == 0) ? Wq : (z == 1) ? Wk : Wv;
  unsigned short* o = Bpack + (size_t)z * (1024 * 1024);
  const int r = t >> 6, c = t & 63;
#pragma unroll
  for (int i = 0; i < 16; ++i) {
    const int row = i * 4 + r;
    tile[row][c] = f2bf(W[(size_t)(k0 + row) * 1024 + n0 + c]);
  }
  __syncthreads();
  const int q = t >> 6, l = t & 63, lc = l & 15, lg = l >> 4;
#pragma unroll
  for (int it = 0; it < 2; ++it) {
    const int nt = (rem >> 4) * 4 + q;
    const int kt = (rem & 15) * 2 + it;
    unsigned short buf[8];
#pragma unroll
    for (int e = 0; e < 8; ++e)
      buf[e] = tile[it * 32 + lg * 8 + e][q * 16 + lc];
    *(uint4*)(o + (size_t)nt * 16384 + kt * 512 + l * 8) = *(uint4*)buf;
  }
}

// ---------- kernel 2: QKV GEMM, 8x4 wave tile + sched_barrier-pinned prefetch ----------
// R17 proved the 8x4 tile correct and 1.68x per-wave efficient, but the compiler
// compacted (VGPR 120) and sank the prefetch loads -> latency exposed at 6 waves/CU.
// Fix: sched_barrier(0) pins after each load group and each MFMA cluster so the
// 12 next-set loads issue BEFORE the 32-MFMA block (coarse pins only, 2/iter).
__global__ __launch_bounds__(128, 2) void qkv_gemm(
    const unsigned short* __restrict__ Apack,
    const unsigned short* __restrict__ Bpack,
    const float* __restrict__ bq, const float* __restrict__ bk,
    const float* __restrict__ bv,
    unsigned short* __restrict__ Qb,
    unsigned short* __restrict__ Kpk,
    unsigned short* __restrict__ Vpk) {
  const int id = blockIdx.x;
  const int xcd = id & 7;
  const int j = id >> 3;
  const int mx = (xcd & 3) * 8 + (j & 7);
  const int v = (j >> 3) * 2 + (xcd >> 2);
  const int nx = v & 7;
  const int z = v >> 3;

  const float* bias = (z == 0) ? bq : (z == 1) ? bk : bv;
  const float scale = (z == 0) ? 0.125f * 1.44269504089f : 1.0f;
  const int m0 = mx * 128, n0 = nx * 128;
  const int t = threadIdx.x;
  const int wc = t >> 6, l = t & 63;
  const int lg = l >> 4, lc = l & 15;

  const unsigned short* Ap = Apack + (size_t)(mx * 8) * 16384 + l * 8;
  const unsigned short* Bp = Bpack + (size_t)z * (1024 * 1024) +
                             (size_t)(nx * 8 + wc * 4) * 16384 + l * 8;

  f32x4 acc[8][4] = {};
  bf16x8 a0[8], b0[4], a1[8], b1[4];

#pragma unroll
  for (int m = 0; m < 8; ++m) a0[m] = *(const bf16x8*)(Ap + m * 16384);
#pragma unroll
  for (int n = 0; n < 4; ++n) b0[n] = *(const bf16x8*)(Bp + n * 16384);

  for (int kk = 0; kk < 16; ++kk) {
    const int kt = kk * 2;
    // prefetch kt+1 -> set1; pin so these issue before set0's MFMAs
#pragma unroll
    for (int m = 0; m < 8; ++m)
      a1[m] = *(const bf16x8*)(Ap + m * 16384 + (kt + 1) * 512);
#pragma unroll
    for (int n = 0; n < 4; ++n)
      b1[n] = *(const bf16x8*)(Bp + n * 16384 + (kt + 1) * 512);
    __builtin_amdgcn_sched_barrier(0);
#pragma unroll
    for (int m = 0; m < 8; ++m)
#pragma unroll
      for (int n = 0; n < 4; ++n)
        acc[m][n] = mfma16(a0[m], b0[n], acc[m][n]);
    __builtin_amdgcn_sched_barrier(0);
    // prefetch kt+2 -> set0; pin before set1's MFMAs
    if (kk < 15) {
#pragma unroll
      for (int m = 0; m < 8; ++m)
        a0[m] = *(const bf16x8*)(Ap + m * 16384 + (kt + 2) * 512);
#pragma unroll
      for (int n = 0; n < 4; ++n)
        b0[n] = *(const bf16x8*)(Bp + n * 16384 + (kt + 2) * 512);
      __builtin_amdgcn_sched_barrier(0);
    }
#pragma unroll
    for (int m = 0; m < 8; ++m)
#pragma unroll
      for (int n = 0; n < 4; ++n)
        acc[m][n] = mfma16(a1[m], b1[n], acc[m][n]);
    __builtin_amdgcn_sched_barrier(0);
  }

  if (z == 0) {
#pragma unroll
    for (int n = 0; n < 4; ++n) {
      const int col = n0 + wc * 64 + n * 16 + lc;
      const float bs = bias[col];
#pragma unroll
      for (int m = 0; m < 8; ++m)
#pragma unroll
        for (int r = 0; r < 4; ++r) {
          const int row = m0 + m * 16 + lg * 4 + r;
          Qb[(size_t)row * 1024 + col] = f2bf((acc[m][n][r] + bs) * scale);
        }
    }
  } else if (z == 1) {
    // Kpack: idx = ((bh*32+kb)*4+s)*512 + (lo+hi*32)*8 + e
#pragma unroll
    for (int n = 0; n < 4; ++n) {
      const int col = n0 + wc * 64 + n * 16 + lc;
      const float bs = bias[col];
      const int h = col >> 6, s = (col >> 4) & 3, hi = (col >> 3) & 1, e = col & 7;
#pragma unroll
      for (int m = 0; m < 8; ++m)
#pragma unroll
        for (int r = 0; r < 4; ++r) {
          const int row = m0 + m * 16 + lg * 4 + r;
          const int bh = (row >> 10) * 16 + h, tl = row & 1023;
          const int kb = tl >> 5, lo = tl & 31;
          Kpk[(size_t)(((bh * 32 + kb) * 4 + s) * 512) + (lo + hi * 32) * 8 + e] =
              f2bf(acc[m][n][r] + bs);
        }
    }
  } else {
    // Vpack: idx = ((bh*16+kt)*8+g*4+sv)*512 + (lo+hiv*32)*8 + ev
#pragma unroll
    for (int n = 0; n < 4; ++n) {
      const int col = n0 + wc * 64 + n * 16 + lc;
      const float bs = bias[col];
      const int h = col >> 6, g = (col >> 5) & 1, lo = col & 31;
#pragma unroll
      for (int m = 0; m < 8; ++m)
#pragma unroll
        for (int r = 0; r < 4; ++r) {
          const int row = m0 + m * 16 + lg * 4 + r;
          const int bh = (row >> 10) * 16 + h, tl = row & 1023;
          const int kt = tl >> 6, within = tl & 63;
          const int sv = within >> 4, hiv = (within >> 3) & 1, ev = within & 7;
          Vpk[(size_t)(((bh * 16 + kt) * 8 + g * 4 + sv) * 512) +
              (lo + hiv * 32) * 8 + ev] = f2bf(acc[m][n][r] + bs);
        }
    }
  }
}

// ---------- kernel 3: flash attention (R13/R12/R5 listing verbatim; measured ~24us) ----------
__global__ __launch_bounds__(256, 2) void attn_kernel(
    const unsigned short* __restrict__ Qb,     // (B,S,H,D) bf16, pre-scaled log2e/sqrt(D)
    const unsigned short* __restrict__ Kpack,  // [bh][kb][s][lane] 16B
    const unsigned short* __restrict__ Vpack,  // [bh][kt][g][s][lane] 16B
    const int* __restrict__ amask,             // (B,S)
    const float* __restrict__ lhm,             // (H)
    float* __restrict__ out) {                 // (B,S,HID) fp32
  const int id = blockIdx.x;
  const int swzid = (id & 7) * 64 + (id >> 3);  // 8 bh per XCD
  const int qt = swzid & 7;
  const int bh = swzid >> 3;
  const int b = bh >> 4, h = bh & 15;
  const int t = threadIdx.x;
  const int w = t >> 6, l = t & 63;
  const int lo = l & 31, hi = l >> 5;
  const int q0 = qt * 128 + w * 32;

  const unsigned short* Kp = Kpack + (size_t)bh * 65536 + l * 8;
  const unsigned short* Vp = Vpack + (size_t)bh * 65536 + l * 8;

  const unsigned short* qp = Qb + (size_t)(b * SEQ + q0 + lo) * HIDD + h * DH + hi * 8;
  bf16x8 qf[4];
#pragma unroll
  for (int s = 0; s < 4; ++s) qf[s] = *(const bf16x8*)(qp + s * 16);

  bool needmask;
  {
    unsigned long long mm = ~0ull;
#pragma unroll
    for (int tk = 0; tk < 16; ++tk)
      mm &= __ballot(amask[b * SEQ + tk * 64 + l] > 0);
    needmask = (mm != ~0ull);
  }

  float m_run = -INFINITY, l_run = 0.f;
  f32x16 acc0 = {}, acc1 = {};

  bf16x8 kf0[4], kf1[4], vf0[4], vf1[4];

#pragma unroll
  for (int s = 0; s < 4; ++s) {
    kf0[s] = *(const bf16x8*)(Kp + (s)*512);
    kf1[s] = *(const bf16x8*)(Kp + (4 + s) * 512);
  }

  for (int tk = 0; tk < 16; ++tk) {
#pragma unroll
    for (int s = 0; s < 4; ++s) {
      vf0[s] = *(const bf16x8*)(Vp + (size_t)(tk * 8 + s) * 512);
      vf1[s] = *(const bf16x8*)(Vp + (size_t)(tk * 8 + 4 + s) * 512);
    }

    // ---- S^T = K . Q^T ----
    f32x16 sg0 = {}, sg1 = {};
    __builtin_amdgcn_s_setprio(1);
#pragma unroll
    for (int s = 0; s < 4; ++s) {
      sg0 = mfma32(kf0[s], qf[s], sg0);
      sg1 = mfma32(kf1[s], qf[s], sg1);
    }
    __builtin_amdgcn_s_setprio(0);

    if (tk < 15) {
#pragma unroll
      for (int s = 0; s < 4; ++s) {
        kf0[s] = *(const bf16x8*)(Kp + (size_t)(tk * 8 + 8 + s) * 512);
        kf1[s] = *(const bf16x8*)(Kp + (size_t)(tk * 8 + 12 + s) * 512);
      }
    }

    // ---- row max ----
    float t0[8];
#pragma unroll
    for (int i = 0; i < 8; ++i)
      t0[i] = fmaxf(fmaxf(sg0[i], sg0[i + 8]), fmaxf(sg1[i], sg1[i + 8]));
    float t1 = fmaxf(fmaxf(fmaxf(t0[0], t0[1]), fmaxf(t0[2], t0[3])),
                     fmaxf(fmaxf(t0[4], t0[5]), fmaxf(t0[6], t0[7])));
    const float pmax = fmaxf(t1, __shfl_xor(t1, 32));

    // ---- defer-max (T13) ----
    if (!__all(pmax <= m_run + 8.f)) {
      const float mnew = fmaxf(m_run, pmax);
      const float sc = __builtin_amdgcn_exp2f(m_run - mnew);
      m_run = mnew;
      l_run *= sc;
#pragma unroll
      for (int g = 0; g < 16; ++g) {
        const int rowi = (g & 3) + 8 * (g >> 2) + 4 * hi;
        const float scr = __shfl(sc, rowi);
        acc0[g] *= scr;
        acc1[g] *= scr;
      }
    }

    // ---- p = exp2(s - m) ----
#pragma unroll
    for (int g = 0; g < 16; ++g) {
      sg0[g] = __builtin_amdgcn_exp2f(sg0[g] - m_run);
      sg1[g] = __builtin_amdgcn_exp2f(sg1[g] - m_run);
    }

    // ---- mask (slow path only) ----
    if (needmask) {
      const int mv = amask[b * SEQ + tk * 64 + l];
      const unsigned long long m64 = __ballot(mv > 0);
      if (m64 != ~0ull) {
#pragma unroll
        for (int g = 0; g < 16; ++g) {
          const int krow = (g & 3) + 8 * (g >> 2) + 4 * hi;
          if (!((m64 >> krow) & 1)) sg0[g] = 0.f;
          if (!((m64 >> (krow + 32)) & 1)) sg1[g] = 0.f;
        }
      }
    }

    // ---- row sum ----
    float s0[8];
#pragma unroll
    for (int i = 0; i < 8; ++i)
      s0[i] = (sg0[i] + sg0[i + 8]) + (sg1[i] + sg1[i + 8]);
    float rs = ((s0[0] + s0[1]) + (s0[2] + s0[3])) +
               ((s0[4] + s0[5]) + (s0[6] + s0[7]));
    rs += __shfl_xor(rs, 32);
    l_run += rs;

    // ---- P -> bf16 PA fragments (T12) ----
    auto mk = [](float a0, float a1, float a2, float a3,
                 float a4, float a5, float a6, float a7) -> bf16x8 {
      u32 x = cvtpk(a0, a1), y = cvtpk(a2, a3);
      u32 a = cvtpk(a4, a5), b2 = cvtpk(a6, a7);
      plswap(x, a);
      plswap(y, b2);
      union { u32 u[4]; bf16x8 v; } fu;
      fu.u[0] = x; fu.u[1] = y; fu.u[2] = a; fu.u[3] = b2;
      return fu.v;
    };
    const bf16x8 pa0 = mk(sg0[0], sg0[1], sg0[2], sg0[3], sg0[4], sg0[5], sg0[6], sg0[7]);
    const bf16x8 pa1 = mk(sg0[8], sg0[9], sg0[10], sg0[11], sg0[12], sg0[13], sg0[14], sg0[15]);
    const bf16x8 pa2 = mk(sg1[0], sg1[1], sg1[2], sg1[3], sg1[4], sg1[5], sg1[6], sg1[7]);
    const bf16x8 pa3 = mk(sg1[8], sg1[9], sg1[10], sg1[11], sg1[12], sg1[13], sg1[14], sg1[15]);

    // ---- PV: acc += P . V ----
    __builtin_amdgcn_s_setprio(1);
#pragma unroll
    for (int s = 0; s < 4; ++s) {
      const bf16x8 paf = (s == 0) ? pa0 : (s == 1) ? pa1 : (s == 2) ? pa2 : pa3;
      acc0 = mfma32(paf, vf0[s], acc0);
      acc1 = mfma32(paf, vf1[s], acc1);
    }
    __builtin_amdgcn_s_setprio(0);
  }

  // ---- epilogue ----
  const float hm = lhm[h];
  const float inv = hm / l_run;
  float* ob = out + (size_t)(b * SEQ + q0) * HIDD + h * DH + lo;
#pragma unroll
  for (int g = 0; g < 16; ++g) {
    const int rowi = (g & 3) + 8 * (g >> 2) + 4 * hi;
    const float iv = __shfl(inv, rowi);
    ob[(size_t)rowi * HIDD] = acc0[g] * iv;
    ob[(size_t)rowi * HIDD + 32] = acc1[g] * iv;
  }
}

// ---------- launch ----------
extern "C" void kernel_launch(void* const* d_in, const int* in_sizes, int n_in,
                              void* d_out, int out_size, void* d_ws, size_t ws_size,
                              hipStream_t stream) {
  const float* hs = (const float*)d_in[0];
  const int* amask = (const int*)d_in[1];
  const float* lhm = (const float*)d_in[2];
  const float* Wq = (const float*)d_in[3];
  const float* bq = (const float*)d_in[4];
  const float* Wk = (const float*)d_in[5];
  const float* bk = (const float*)d_in[6];
  const float* Wv = (const float*)d_in[7];
  const float* bv = (const float*)d_in[8];
  float* out = (float*)d_out;

  char* ws = (char*)d_ws;
  unsigned short* Apack = (unsigned short*)ws;                  // 8 MB
  unsigned short* Bpack = (unsigned short*)(ws + (8u << 20));   // 6 MB
  unsigned short* Qb = (unsigned short*)(ws + (14u << 20));     // 8 MB
  unsigned short* Kpk = (unsigned short*)(ws + (22u << 20));    // 8 MB
  unsigned short* Vpk = (unsigned short*)(ws + (30u << 20));    // 8 MB

  prep<<<1024, 256, 0, stream>>>(hs, Apack, Wq, Wk, Wv, Bpack);
  qkv_gemm<<<768, 128, 0, stream>>>(Apack, Bpack, bq, bk, bv, Qb, Kpk, Vpk);
  attn_kernel<<<512, 256, 0, stream>>>(Qb, Kpk, Vpk, amask, lhm, out);
}